// Round 2
// baseline (491.328 us; speedup 1.0000x reference)
//
#include <hip/hip_runtime.h>
#include <hip/hip_bf16.h>

// ---------------------------------------------------------------------------
// BinarizedLayer: out[m,n] = sum_k x[m,k] * wbin[n,k] + bias[n]
//   wbin = (w < (upper-lower)) ? lower : upper,  upper=max(c1,c2), lower=min
// M=16384 (B*S), K=1024 (DIN), N=4096 (DOUT). fp32 in/out.
//
// R1 changes vs R0 (208us GEMM, 661 TF, 1.68e7 LDS bank-conflict cycles):
//  - 32x32x16 MFMA (2x2 per wave) instead of 16x16x32 (4x4): higher matrix-
//    pipe rate (2495 vs ~2100 TF ubench), half the MFMA instrs, half the
//    ds_read instrs per K-chunk.
//  - XOR-swizzled LDS staging: global chunk (r, q^s(r)) stored at LDS chunk
//    (r, q), s(r)=(r>>1)&3. Fragment ds_read_b128 row-walk (stride 64B) goes
//    from 16-way bank aliasing to perfectly balanced 8/bank-group.
//    (LDS padding is impossible: global_load_lds dest is uniform-base+lane*16.)
// ---------------------------------------------------------------------------

typedef __bf16 bf16x8 __attribute__((ext_vector_type(8)));
typedef float  f32x16 __attribute__((ext_vector_type(16)));

__device__ inline unsigned short f2bf(float f) {
    unsigned int u = __float_as_uint(f);
    u += 0x7FFFu + ((u >> 16) & 1u);   // round-to-nearest-even
    return (unsigned short)(u >> 16);
}

// ---- prep: x fp32 -> bf16 -------------------------------------------------
__global__ void cvt_x_kernel(const float4* __restrict__ in,
                             ushort4* __restrict__ out, int n4) {
    int stride = gridDim.x * blockDim.x;
    for (int i = blockIdx.x * blockDim.x + threadIdx.x; i < n4; i += stride) {
        float4 v = in[i];
        ushort4 o;
        o.x = f2bf(v.x); o.y = f2bf(v.y); o.z = f2bf(v.z); o.w = f2bf(v.w);
        out[i] = o;
    }
}

// ---- prep: binarize w and cast to bf16 ------------------------------------
__global__ void bin_w_kernel(const float4* __restrict__ w,
                             ushort4* __restrict__ out,
                             const float* __restrict__ c1,
                             const float* __restrict__ c2, int n4) {
    const float a = c1[0], b = c2[0];
    const float upper  = fmaxf(a, b);
    const float lower  = fminf(a, b);
    const float middle = upper - lower;   // threshold, exactly as reference
    const unsigned short lo16 = f2bf(lower);
    const unsigned short up16 = f2bf(upper);
    int stride = gridDim.x * blockDim.x;
    for (int i = blockIdx.x * blockDim.x + threadIdx.x; i < n4; i += stride) {
        float4 v = w[i];
        ushort4 o;
        o.x = (v.x < middle) ? lo16 : up16;
        o.y = (v.y < middle) ? lo16 : up16;
        o.z = (v.z < middle) ? lo16 : up16;
        o.w = (v.w < middle) ? lo16 : up16;
        out[i] = o;
    }
}

// ---- async 16B global -> LDS ----------------------------------------------
__device__ inline void async16(void* lds, const void* g) {
    __builtin_amdgcn_global_load_lds(
        (const __attribute__((address_space(1))) void*)g,
        (__attribute__((address_space(3))) void*)lds,
        16, 0, 0);
}

// ---- GEMM: C[m,n] = sum_k A[m,k]*B[n,k] + bias[n] (A,B bf16 bits, C fp32) -
// 128x128 tile, BK=32, 256 threads = 4 waves in 2x2; each wave computes a
// 64x64 sub-tile as 2x2 of v_mfma_f32_32x32x16_bf16.
__global__ __launch_bounds__(256) void gemm_bin(
        const ushort* __restrict__ A,   // [M][K] bf16 bits
        const ushort* __restrict__ B,   // [N][K] bf16 bits
        const float*  __restrict__ bias,
        float* __restrict__ C,
        int M, int N, int K) {
    __shared__ ushort As[128 * 32];     // two 64-row half-tiles of 2048 ushorts
    __shared__ ushort Bs[128 * 32];

    const int tid  = threadIdx.x;
    const int wave = tid >> 6;
    const int lane = tid & 63;
    const int l31  = lane & 31;
    const int lhi  = lane >> 5;         // 0/1

    const int bn = blockIdx.x;          // N-block (fastest -> A-row reuse)
    const int bm = blockIdx.y;
    const int row0 = bm * 128;
    const int col0 = bn * 128;

    const int wm = (wave & 1) * 64;     // wave row offset in tile
    const int wn = (wave >> 1) * 64;    // wave col offset in tile

    f32x16 acc[2][2];
#pragma unroll
    for (int i = 0; i < 2; ++i)
#pragma unroll
        for (int j = 0; j < 2; ++j)
#pragma unroll
            for (int r = 0; r < 16; ++r)
                acc[i][j][r] = 0.f;

    // ---- staging: thread t owns LDS chunk t (16B) of each 64-row half-tile.
    // LDS chunk (r, c) must hold global k-chunk (c ^ s(r)), s(r) = (r>>1)&3.
    const int sr = tid >> 2;                         // row 0..63 within half
    const int sq = (tid & 3) ^ ((sr >> 1) & 3);      // swizzled global chunk
    const int sc = sq * 8;                           // col in elements
    const ushort* a0 = A + (size_t)(row0 + sr) * K + sc;
    const ushort* a1 = A + (size_t)(row0 + 64 + sr) * K + sc;
    const ushort* b0 = B + (size_t)(col0 + sr) * K + sc;
    const ushort* b1 = B + (size_t)(col0 + 64 + sr) * K + sc;

    // wave-uniform LDS bases (lanes land at base + lane*16B)
    ushort* asd0 = &As[wave * 512];
    ushort* asd1 = &As[2048 + wave * 512];
    ushort* bsd0 = &Bs[wave * 512];
    ushort* bsd1 = &Bs[2048 + wave * 512];

    // ---- fragment addressing -------------------------------------------
    // 32x32x16 A/B layout: m(or n) = lane&31, k = (lane>>5)*8 + j.
    // Local row in half-tile: ra = i*32 + l31; swizzle key s(ra) =
    // ((i*32+l31)>>1)&3 = (l31>>1)&3  (i*32 contributes 0 mod 4).
    const int sKey  = (l31 >> 1) & 3;
    const int aHalf = (wm >> 6) * 2048;   // which 64-row half-buffer
    const int bHalf = (wn >> 6) * 2048;

    for (int k0 = 0; k0 < K; k0 += 32) {
        async16(asd0, a0 + k0);
        async16(asd1, a1 + k0);
        async16(bsd0, b0 + k0);
        async16(bsd1, b1 + k0);
        __syncthreads();

        bf16x8 af[2][2], bfr[2][2];
#pragma unroll
        for (int h = 0; h < 2; ++h) {
            const int q  = (h << 1) | lhi;          // global k-chunk wanted
            const int co = ((q ^ sKey) << 3);       // swizzled LDS col (elems)
#pragma unroll
            for (int i = 0; i < 2; ++i)
                af[i][h] = *(const bf16x8*)&As[aHalf + (i * 32 + l31) * 32 + co];
#pragma unroll
            for (int j = 0; j < 2; ++j)
                bfr[j][h] = *(const bf16x8*)&Bs[bHalf + (j * 32 + l31) * 32 + co];
        }

#pragma unroll
        for (int h = 0; h < 2; ++h)
#pragma unroll
            for (int i = 0; i < 2; ++i)
#pragma unroll
                for (int j = 0; j < 2; ++j)
                    acc[i][j] = __builtin_amdgcn_mfma_f32_32x32x16_bf16(
                        af[i][h], bfr[j][h], acc[i][j], 0, 0, 0);

        __syncthreads();
    }

    // ---- epilogue: 32x32 C/D layout col=lane&31, row=(reg&3)+8*(reg>>2)+4*lhi
#pragma unroll
    for (int j = 0; j < 2; ++j) {
        const int col = col0 + wn + j * 32 + l31;
        const float bz = bias[col];
#pragma unroll
        for (int i = 0; i < 2; ++i) {
            const int rbase = row0 + wm + i * 32 + 4 * lhi;
#pragma unroll
            for (int reg = 0; reg < 16; ++reg) {
                const int row = rbase + (reg & 3) + 8 * (reg >> 2);
                C[(size_t)row * N + col] = acc[i][j][reg] + bz;
            }
        }
    }
}

extern "C" void kernel_launch(void* const* d_in, const int* in_sizes, int n_in,
                              void* d_out, int out_size, void* d_ws, size_t ws_size,
                              hipStream_t stream) {
    const float* x    = (const float*)d_in[0];   // [M][K]
    const float* w    = (const float*)d_in[1];   // [N][K]
    const float* c1   = (const float*)d_in[2];
    const float* c2   = (const float*)d_in[3];
    const float* bias = (const float*)d_in[4];   // [N]
    float* out = (float*)d_out;

    const int DOUT = in_sizes[4];                // 4096
    const int DIN  = in_sizes[1] / DOUT;         // 1024
    const int M    = in_sizes[0] / DIN;          // 16384
    const int N    = DOUT;
    const int K    = DIN;

    // workspace layout: x_bf16 (M*K ushort) then w_bf16 (N*K ushort) = 40 MB
    ushort* xb = (ushort*)d_ws;
    ushort* wb = xb + (size_t)M * K;

    const int nx4 = (M * K) / 4;
    const int nw4 = (N * K) / 4;
    cvt_x_kernel<<<4096, 256, 0, stream>>>((const float4*)x, (ushort4*)xb, nx4);
    bin_w_kernel<<<1024, 256, 0, stream>>>((const float4*)w, (ushort4*)wb, c1, c2, nw4);

    dim3 grid(N / 128, M / 128);   // (32, 128)
    gemm_bin<<<grid, 256, 0, stream>>>(xb, wb, bias, out, M, N, K);
}